// Round 1
// baseline (178.175 us; speedup 1.0000x reference)
//
#include <hip/hip_runtime.h>
#include <limits.h>

#define BLOCK 256
#define CHUNK 2
#define SPAN  64
#define PERSIST_BLOCKS 2048   // 8 blocks/CU x 256 CUs; NO min-waves launch bound!

typedef float v2f __attribute__((ext_vector_type(2)));

__device__ __forceinline__ v2f pk_fma(v2f a, v2f b, v2f c) {
    return __builtin_elementwise_fma(a, b, c);
}
__device__ __forceinline__ v2f sp(float w){ v2f r; r.x = w; r.y = w; return r; }
__device__ __forceinline__ float leaky_(float x){ return x >= 0.f ? x : 0.01f*x; }

// Packed weight-table layout (floats), built once by prep, block-copied to LDS.
// Atom-axis packing: weights are read as float4 rows (b128, wave-uniform
// broadcast) and used as scalar multiplicands; biases stored pre-duplicated.
#define L_W2A    0       // 32*12 : w2a rows [k][j], j<9 valid, pad 3
#define L_W2BT   384     // 32*16 : w2bT[k][m] = w2b[m*32+k]
#define L_W2CT   896     // 16*8  : w2cT[m][p] = w2c[p*16+m], pad p<8
#define L_B2B2   1024    // 32    : duplicated pairs {b2b[m], b2b[m]}
#define L_B2C2   1056    // 16    : duplicated pairs {b2c[p], b2c[p]}, pad
#define L_W013   1072    // 48    : 3 mats x 3 rows x4: (w,w,w,b) for w0,w1,w1n
#define WTAB_SZ  1120
#define L_ACC    1120    // SPAN*6 block-local segment accumulator
#define L_TOT    (1120 + SPAN*6)

// ---------------- Kernel A: per-structure precompute + weight packing ------
__global__ void prep_kernel(const float* __restrict__ cell,
                            const float* __restrict__ w2a,
                            const float* __restrict__ b2a,
                            const float* __restrict__ w2b,
                            const float* __restrict__ w2c,
                            const float* __restrict__ w0, const float* __restrict__ b0,
                            const float* __restrict__ w1, const float* __restrict__ b1,
                            const float* __restrict__ w1n, const float* __restrict__ b1n,
                            const float* __restrict__ b2b, const float* __restrict__ b2c,
                            float* __restrict__ ci_out,
                            float* __restrict__ cc_out,
                            float* __restrict__ wtab,
                            float* __restrict__ out_zero,
                            int S)
{
    __shared__ float sw[2880];          // all of w2a [32][90]
    int tid = threadIdx.x;
    int gid = blockIdx.x * blockDim.x + tid;

    #pragma unroll
    for (int t = 0; t < 3; t++) {
        int idx = tid + t*256;
        if (idx < 720) ((float4*)sw)[idx] = ((const float4*)w2a)[idx];
    }

    if (gid < S * 6) out_zero[gid] = 0.f;

    // ---- wtab packing (few threads; scattered loads negligible) ----
    if (gid < 384) {
        int k = gid / 12, j = gid % 12;
        wtab[gid] = (j < 9) ? w2a[k*90 + j] : 0.f;
    } else if (gid < 896) {
        int t = gid - 384; int k = t >> 4, m = t & 15;
        wtab[gid] = w2b[m*32 + k];
    } else if (gid < 1024) {
        int t = gid - 896; int m = t >> 3, p = t & 7;
        wtab[gid] = (p < 6) ? w2c[p*16 + m] : 0.f;
    } else if (gid < 1056) {
        int t = gid - 1024; wtab[gid] = b2b[t >> 1];
    } else if (gid < 1072) {
        int t = gid - 1056; int p = t >> 1;
        wtab[gid] = (p < 6) ? b2c[p] : 0.f;
    } else if (gid < 1120) {
        int t = gid - 1072;
        if (t < 36) {
            int mat = t / 12, rr = t % 12, r = rr >> 2, c = rr & 3;
            const float* W = (mat == 0) ? w0 : (mat == 1) ? w1 : w1n;
            const float* B = (mat == 0) ? b0 : (mat == 1) ? b1 : b1n;
            wtab[gid] = (c < 3) ? W[r*3 + c] : B[r];
        } else wtab[gid] = 0.f;
    }

    __syncthreads();

    int s = gid >> 5;
    if (s >= S) return;
    int k = gid & 31;

    float cr[9];
    #pragma unroll
    for (int j = 0; j < 9; j++) cr[j] = cell[s*9 + j];

    if (k == 0) {
        float a=cr[0],b=cr[1],c=cr[2],d=cr[3],e=cr[4],f=cr[5],g=cr[6],h=cr[7],i=cr[8];
        float A = e*i - f*h;
        float B = f*g - d*i;
        float C = d*h - e*g;
        float det = a*A + b*B + c*C;
        float r = 1.0f / det;
        float* o = ci_out + s*12;
        o[0] = A*r;         o[1] = (c*h - b*i)*r; o[2] = (b*f - c*e)*r;
        o[3] = B*r;         o[4] = (a*i - c*g)*r; o[5] = (c*d - a*f)*r;
        o[6] = C*r;         o[7] = (b*g - a*h)*r; o[8] = (a*e - b*d)*r;
        o[9] = 0.f; o[10] = 0.f; o[11] = 0.f;
    }

    float acc = b2a[k];
    const float* wr = sw + k*90 + 9;     // LDS
    #pragma unroll
    for (int j1 = 0; j1 < 9; j1++) {
        float c1 = cr[j1];
        #pragma unroll
        for (int j2 = 0; j2 < 9; j2++)
            acc = fmaf(c1 * cr[j2], wr[j1*9 + j2], acc);
    }
    cc_out[s*32 + k] = acc;
}

// ---- one k-step of fused L1(relu)+L2: atom-pair packed -------------------
// u = relu(cc + sum_j h2[j]*w2a[k][j]) ; vv[m] += u * w2bT[k][m]
__device__ __forceinline__ void do_k(const float* ldsw, int k, float cA, float cB,
                                     const v2f* h2, v2f* vv)
{
    const float4* wa = (const float4*)(ldsw + L_W2A + k*12);
    float4 a0 = wa[0], a1 = wa[1], a2 = wa[2];
    v2f u; u.x = cA; u.y = cB;
    u = pk_fma(h2[0], sp(a0.x), u);
    u = pk_fma(h2[1], sp(a0.y), u);
    u = pk_fma(h2[2], sp(a0.z), u);
    u = pk_fma(h2[3], sp(a0.w), u);
    u = pk_fma(h2[4], sp(a1.x), u);
    u = pk_fma(h2[5], sp(a1.y), u);
    u = pk_fma(h2[6], sp(a1.z), u);
    u = pk_fma(h2[7], sp(a1.w), u);
    u = pk_fma(h2[8], sp(a2.x), u);
    v2f zero = 0.f;
    u = __builtin_elementwise_max(u, zero);
    const float4* wb = (const float4*)(ldsw + L_W2BT + k*16);
    float4 b0 = wb[0], b1 = wb[1], b2 = wb[2], b3 = wb[3];
    vv[0]  = pk_fma(u, sp(b0.x), vv[0]);
    vv[1]  = pk_fma(u, sp(b0.y), vv[1]);
    vv[2]  = pk_fma(u, sp(b0.z), vv[2]);
    vv[3]  = pk_fma(u, sp(b0.w), vv[3]);
    vv[4]  = pk_fma(u, sp(b1.x), vv[4]);
    vv[5]  = pk_fma(u, sp(b1.y), vv[5]);
    vv[6]  = pk_fma(u, sp(b1.z), vv[6]);
    vv[7]  = pk_fma(u, sp(b1.w), vv[7]);
    vv[8]  = pk_fma(u, sp(b2.x), vv[8]);
    vv[9]  = pk_fma(u, sp(b2.y), vv[9]);
    vv[10] = pk_fma(u, sp(b2.z), vv[10]);
    vv[11] = pk_fma(u, sp(b2.w), vv[11]);
    vv[12] = pk_fma(u, sp(b3.x), vv[12]);
    vv[13] = pk_fma(u, sp(b3.y), vv[13]);
    vv[14] = pk_fma(u, sp(b3.z), vv[14]);
    vv[15] = pk_fma(u, sp(b3.w), vv[15]);
}

// ---------------- Kernel B: persistent per-atom MLP + segment sum ----------
__global__ __launch_bounds__(BLOCK)
void main_kernel(const float* __restrict__ atom_prop,
                 const float* __restrict__ pos,
                 const int*   __restrict__ batch,
                 const float* __restrict__ ci_ws,
                 const float* __restrict__ cc_ws,
                 const float* __restrict__ wtab,
                 float* __restrict__ out,
                 int N, int S, int ntiles)
{
    __shared__ float lds[L_TOT];
    int tid = threadIdx.x;

    // coalesced float4 staging of the whole weight table (280 float4)
    ((float4*)lds)[tid] = ((const float4*)wtab)[tid];
    if (tid < 24) ((float4*)lds)[256 + tid] = ((const float4*)wtab)[256 + tid];

    for (int tile = blockIdx.x; tile < ntiles; tile += gridDim.x) {
        long long blk_base = (long long)tile * (BLOCK * CHUNK);
        int s0 = batch[(blk_base < N) ? blk_base : (N - 1)];

        for (int t = tid; t < SPAN*6; t += BLOCK) lds[L_ACC + t] = 0.f;
        __syncthreads();

        long long base = blk_base + (long long)tid * CHUNK;
        bool any = (base < N);

        int   sv[CHUNK];
        float PX[CHUNK], PY[CHUNK], PZ[CHUNK];
        float AX[CHUNK], AY[CHUNK], AZ[CHUNK];

        if (any && base + CHUNK <= N) {
            int2 bb = *(const int2*)(batch + base);
            sv[0] = bb.x; sv[1] = bb.y;
            const float2* pp = (const float2*)(pos + 3*base);
            float2 p0 = pp[0], p1 = pp[1], p2 = pp[2];
            PX[0]=p0.x; PY[0]=p0.y; PZ[0]=p1.x;
            PX[1]=p1.y; PY[1]=p2.x; PZ[1]=p2.y;
            const float2* ap = (const float2*)(atom_prop + 3*base);
            float2 a0 = ap[0], a1 = ap[1], a2 = ap[2];
            AX[0]=a0.x; AY[0]=a0.y; AZ[0]=a1.x;
            AX[1]=a1.y; AY[1]=a2.x; AZ[1]=a2.y;
        } else {
            #pragma unroll
            for (int t = 0; t < CHUNK; t++) {
                long long i = base + t;
                bool ok = any && (i < N);
                sv[t] = ok ? batch[i] : -1;
                PX[t] = ok ? pos[3*i]   : 0.f;
                PY[t] = ok ? pos[3*i+1] : 0.f;
                PZ[t] = ok ? pos[3*i+2] : 0.f;
                AX[t] = ok ? atom_prop[3*i]   : 0.f;
                AY[t] = ok ? atom_prop[3*i+1] : 0.f;
                AZ[t] = ok ? atom_prop[3*i+2] : 0.f;
            }
        }

        const float* cc0 = cc_ws + (size_t)(sv[0] < 0 ? 0 : sv[0])*32;
        const float* cc1 = cc_ws + (size_t)(sv[1] < 0 ? 0 : sv[1])*32;

        // ---- phase 1: per-atom h, then atom-pair pack ----
        float hv[CHUNK][9];
        {
            const float4* q0 = (const float4*)(lds + L_W013);
            const float4* q1 = (const float4*)(lds + L_W013 + 12);
            const float4* q2 = (const float4*)(lds + L_W013 + 24);
            int   cur_s = -1;
            float ci[9];
            #pragma unroll
            for (int t = 0; t < CHUNK; t++) {
                int s = sv[t];
                if (s < 0) {
                    #pragma unroll
                    for (int j = 0; j < 9; j++) hv[t][j] = 0.f;
                    continue;
                }
                if (s != cur_s) {
                    cur_s = s;
                    const float4* cip = (const float4*)(ci_ws + (size_t)s*12);
                    float4 c0 = cip[0], c1 = cip[1], c2 = cip[2];
                    ci[0]=c0.x; ci[1]=c0.y; ci[2]=c0.z; ci[3]=c0.w;
                    ci[4]=c1.x; ci[5]=c1.y; ci[6]=c1.z; ci[7]=c1.w;
                    ci[8]=c2.x;
                }
                float px = PX[t], py = PY[t], pz = PZ[t];
                float ax = AX[t], ay = AY[t], az = AZ[t];

                float f0 = fmaf(px, ci[0], fmaf(py, ci[3], pz*ci[6]));
                float f1 = fmaf(px, ci[1], fmaf(py, ci[4], pz*ci[7]));
                float f2 = fmaf(px, ci[2], fmaf(py, ci[5], pz*ci[8]));
                float t0 = f0 - floorf(f0) - 0.5f;
                float t1 = f1 - floorf(f1) - 0.5f;
                float t2 = f2 - floorf(f2) - 0.5f;

                hv[t][0] = ax; hv[t][1] = ay; hv[t][2] = az;
                #pragma unroll
                for (int r = 0; r < 3; r++) {
                    float4 a0 = q0[r], a1 = q1[r], a2 = q2[r];
                    float ap3 = leaky_(fmaf(ax, a0.x, fmaf(ay, a0.y, fmaf(az, a0.z, a0.w))));
                    float d1  = fmaf(t0, a1.x, fmaf(t1, a1.y, fmaf(t2, a1.z, a1.w)));
                    float d2  = a2.w - fmaf(t0, a2.x, fmaf(t1, a2.y, t2*a2.z));
                    hv[t][3+r] = fmaxf(d1, 0.f) * ap3;
                    hv[t][6+r] = fmaxf(d2, 0.f) * ap3;
                }
            }
        }
        v2f h2[9];
        #pragma unroll
        for (int j = 0; j < 9; j++) { h2[j].x = hv[0][j]; h2[j].y = hv[1][j]; }

        // ---- phase 2: fused L1+relu+L2, atom-pair packed ----
        v2f vv[16];
        {
            const v2f* bb2 = (const v2f*)(lds + L_B2B2);
            #pragma unroll
            for (int m = 0; m < 16; m++) vv[m] = bb2[m];
        }

        #pragma unroll
        for (int kb = 0; kb < 8; kb++) {
            float4 ca = *(const float4*)(cc0 + kb*4);
            float4 cb = *(const float4*)(cc1 + kb*4);
            do_k(lds, kb*4 + 0, ca.x, cb.x, h2, vv);
            do_k(lds, kb*4 + 1, ca.y, cb.y, h2, vv);
            do_k(lds, kb*4 + 2, ca.z, cb.z, h2, vv);
            do_k(lds, kb*4 + 3, ca.w, cb.w, h2, vv);
        }

        // ---- epilogue: leaky, L3 (16->6), atom-pair packed ----
        {
            v2f zero = 0.f, small = 0.01f;
            #pragma unroll
            for (int m = 0; m < 16; m++) {
                v2f mx = __builtin_elementwise_max(vv[m], zero);
                v2f mn = __builtin_elementwise_min(vv[m], zero);
                vv[m] = pk_fma(mn, small, mx);
            }
        }

        v2f oo[6];
        {
            const v2f* bc2 = (const v2f*)(lds + L_B2C2);
            #pragma unroll
            for (int p = 0; p < 6; p++) oo[p] = bc2[p];
        }
        #pragma unroll
        for (int m = 0; m < 16; m++) {
            const float4* wc = (const float4*)(lds + L_W2CT + m*8);
            float4 c0 = wc[0], c1 = wc[1];
            v2f vm = vv[m];
            oo[0] = pk_fma(vm, sp(c0.x), oo[0]);
            oo[1] = pk_fma(vm, sp(c0.y), oo[1]);
            oo[2] = pk_fma(vm, sp(c0.z), oo[2]);
            oo[3] = pk_fma(vm, sp(c0.w), oo[3]);
            oo[4] = pk_fma(vm, sp(c1.x), oo[4]);
            oo[5] = pk_fma(vm, sp(c1.y), oo[5]);
        }

        // ---- per-lane final (key, value); atom0 = .x, atom1 = .y ----
        const int SENT = INT_MAX;
        int fs;
        float fin[6];
        {
            int sA = sv[0], sB = sv[1];
            if (sA < 0) {
                fs = SENT;
                #pragma unroll
                for (int p = 0; p < 6; p++) fin[p] = 0.f;
            } else if (sB == sA) {
                fs = sA;
                #pragma unroll
                for (int p = 0; p < 6; p++) fin[p] = oo[p].x + oo[p].y;
            } else {
                int idx = sA - s0;
                if (idx >= 0 && idx < SPAN) {
                    #pragma unroll
                    for (int p = 0; p < 6; p++) atomicAdd(&lds[L_ACC + idx*6 + p], oo[p].x);
                } else {
                    #pragma unroll
                    for (int p = 0; p < 6; p++) atomicAdd(out + (size_t)sA*6 + p, oo[p].x);
                }
                if (sB >= 0) {
                    fs = sB;
                    #pragma unroll
                    for (int p = 0; p < 6; p++) fin[p] = oo[p].y;
                } else {
                    fs = SENT;
                    #pragma unroll
                    for (int p = 0; p < 6; p++) fin[p] = 0.f;
                }
            }
        }

        // ---- segmented inclusive scan across the wave (keys sorted) ----
        int lane = tid & 63;
        #pragma unroll
        for (int d = 1; d < 64; d <<= 1) {
            int ks = __shfl_up(fs, d);
            bool pred = (lane >= d) && (ks == fs);
            #pragma unroll
            for (int p = 0; p < 6; p++) {
                float vp = __shfl_up(fin[p], d);
                fin[p] += pred ? vp : 0.f;
            }
        }
        {
            int sn = __shfl_down(fs, 1);
            bool tail = (lane == 63) || (sn != fs);
            if (tail && fs != SENT) {
                int idx = fs - s0;
                if (idx >= 0 && idx < SPAN) {
                    #pragma unroll
                    for (int p = 0; p < 6; p++) atomicAdd(&lds[L_ACC + idx*6 + p], fin[p]);
                } else {
                    #pragma unroll
                    for (int p = 0; p < 6; p++) atomicAdd(out + (size_t)fs*6 + p, fin[p]);
                }
            }
        }

        __syncthreads();

        // cooperative flush of LDS accumulator to global (skip untouched slots)
        for (int e = tid; e < SPAN*6; e += BLOCK) {
            int idx = e / 6, p = e - idx*6;
            int sg = s0 + idx;
            float v = lds[L_ACC + e];
            if (sg < S && v != 0.f) atomicAdd(out + (size_t)sg*6 + p, v);
        }

        __syncthreads();   // flush reads done before next tile's zeroing
    }
}

extern "C" void kernel_launch(void* const* d_in, const int* in_sizes, int n_in,
                              void* d_out, int out_size, void* d_ws, size_t ws_size,
                              hipStream_t stream)
{
    const float* atom_prop = (const float*)d_in[0];
    const float* pos       = (const float*)d_in[1];
    const float* cell      = (const float*)d_in[2];
    const int*   batch     = (const int*)  d_in[3];
    const float* w0  = (const float*)d_in[4];
    const float* b0  = (const float*)d_in[5];
    const float* w1  = (const float*)d_in[6];
    const float* b1  = (const float*)d_in[7];
    const float* w1n = (const float*)d_in[8];
    const float* b1n = (const float*)d_in[9];
    const float* w2a = (const float*)d_in[10];
    const float* b2a = (const float*)d_in[11];
    const float* w2b = (const float*)d_in[12];
    const float* b2b = (const float*)d_in[13];
    const float* w2c = (const float*)d_in[14];
    const float* b2c = (const float*)d_in[15];

    int N = in_sizes[3];          // batch has one entry per atom
    int S = in_sizes[2] / 9;      // cell is [S,3,3]

    float* out   = (float*)d_out;
    float* ci_ws = (float*)d_ws;                 // [S*12]
    float* cc_ws = ci_ws + (size_t)S*12;         // [S*32]
    float* wtab  = cc_ws + (size_t)S*32;         // [WTAB_SZ]

    int prep_threads = S * 32;
    prep_kernel<<<(prep_threads + 255)/256, 256, 0, stream>>>(
        cell, w2a, b2a, w2b, w2c, w0, b0, w1, b1, w1n, b1n, b2b, b2c,
        ci_ws, cc_ws, wtab, out, S);

    int tile_atoms = BLOCK * CHUNK;
    int ntiles = (N + tile_atoms - 1) / tile_atoms;
    int grid = ntiles < PERSIST_BLOCKS ? ntiles : PERSIST_BLOCKS;
    main_kernel<<<grid, BLOCK, 0, stream>>>(atom_prop, pos, batch,
                                            ci_ws, cc_ws, wtab, out, N, S, ntiles);
}